// Round 1
// baseline (616.928 us; speedup 1.0000x reference)
//
#include <hip/hip_runtime.h>
#include <cstdint>
#include <cstddef>

// ---------------------------------------------------------------------------
// Plant_Identifier CNN forward, fp32 throughout.
// Pipeline:
//   conv1(2x2,p1)+BN(train)+ReLU+pool2 : stats pass (recompute) + fused pass
//   conv2(3x3,p1)+BN+ReLU+pool2       : store y2, fused per-wave stats
//   conv3(3x3,p1)+BN+ReLU+pool2       : store y3, fused per-wave stats
//   fc1 (50176->256) + ReLU, fc2 (256->5)
// All reductions deterministic (two-stage partials, no float atomics).
// ---------------------------------------------------------------------------

// workspace layout (float offsets)
#define WS_X1   ((size_t)0)          // 12,845,056  x1 [64,16,112,112]; later x3 [64,64,28,28]
#define WS_Y2   ((size_t)12845056)   // 25,690,112  y2 [64,32,112,112]; later y3 [64,64,56,56]
#define WS_X2   ((size_t)38535168)   //  6,422,528  x2 [64,32,56,56]
#define WS_P1   ((size_t)44957696)   // 16*2*6656
#define WS_P2   ((size_t)45170688)   // 32*2*1792
#define WS_P3   ((size_t)45285376)   // 64*2*448
#define WS_ST   ((size_t)45342720)   // scale1(16),shift1(16),scale2(32),shift2(32),scale3(64),shift3(64)
#define WS_FCP  ((size_t)45342976)   // 56*16384 fc1 partials
#define WS_H1   ((size_t)46260480)   // 16384 h1 [64,256]
// total 46,276,864 floats = 185.1 MB

static __device__ __forceinline__ float4 ldg4(const float* p) {
  return *reinterpret_cast<const float4*>(p);
}

// ---------------- conv1 stats pass (recompute, no store) --------------------
// block: (slot-chunk 26, co 16, n 64), 256 thr. thread = 8-px horizontal run.
__global__ __launch_bounds__(256)
void k_conv1_stats(const float* __restrict__ d, const float* __restrict__ w1,
                   const float* __restrict__ b1, float* __restrict__ part) {
  const int n = blockIdx.z, co = blockIdx.y;
  const int slot = blockIdx.x * 256 + threadIdx.x;  // over 225*29 = 6525
  const int oh = slot / 29, q = slot - oh * 29;
  float sum = 0.f, sq = 0.f;
  if (slot < 225 * 29) {
    float pa[2][3][12];  // rows {oh-1, oh}, 3 ci, cols 8q-4..8q+7
    #pragma unroll
    for (int r = 0; r < 2; ++r) {
      const int ih = oh - 1 + r;
      const bool rv = (unsigned)ih < 224u;
      #pragma unroll
      for (int ci = 0; ci < 3; ++ci) {
        const float* rp = d + ((size_t)(n * 3 + ci) * 224 + ih) * 224;
        #pragma unroll
        for (int ch = 0; ch < 3; ++ch) {
          const int c0 = 8 * q - 4 + 4 * ch;
          float4 v = make_float4(0.f, 0.f, 0.f, 0.f);
          if (rv && c0 >= 0 && c0 <= 220) v = ldg4(rp + c0);
          pa[r][ci][ch * 4 + 0] = v.x;
          pa[r][ci][ch * 4 + 1] = v.y;
          pa[r][ci][ch * 4 + 2] = v.z;
          pa[r][ci][ch * 4 + 3] = v.w;
        }
      }
    }
    float wz[3][4];
    #pragma unroll
    for (int ci = 0; ci < 3; ++ci)
      #pragma unroll
      for (int k = 0; k < 4; ++k)
        wz[ci][k] = w1[(co * 3 + ci) * 4 + k];  // uniform -> s_load
    const float bias = b1[co];
    #pragma unroll
    for (int p = 0; p < 8; ++p) {
      if (8 * q + p <= 224) {  // OW = 225
        float v = bias;
        #pragma unroll
        for (int ci = 0; ci < 3; ++ci)
          #pragma unroll
          for (int kh = 0; kh < 2; ++kh)
            #pragma unroll
            for (int kw = 0; kw < 2; ++kw)
              v = fmaf(pa[kh][ci][p + kw + 3], wz[ci][kh * 2 + kw], v);
        sum += v;
        sq = fmaf(v, v, sq);
      }
    }
  }
  #pragma unroll
  for (int m = 1; m < 64; m <<= 1) {
    sum += __shfl_xor(sum, m);
    sq  += __shfl_xor(sq, m);
  }
  if ((threadIdx.x & 63) == 0) {
    const int p = (n * 26 + blockIdx.x) * 4 + (threadIdx.x >> 6);
    part[(co * 2 + 0) * 6656 + p] = sum;
    part[(co * 2 + 1) * 6656 + p] = sq;
  }
}

// ------------- finalize: partials -> per-channel scale/shift ----------------
__global__ __launch_bounds__(256)
void k_finalize(const float* __restrict__ part, int P, double count,
                const float* __restrict__ g, const float* __restrict__ bta,
                float* __restrict__ scale, float* __restrict__ shift) {
  const int c = blockIdx.x;
  double s = 0.0, sq = 0.0;
  for (int i = threadIdx.x; i < P; i += 256) {
    s  += (double)part[(size_t)(c * 2 + 0) * P + i];
    sq += (double)part[(size_t)(c * 2 + 1) * P + i];
  }
  __shared__ double rs[256], rq[256];
  rs[threadIdx.x] = s; rq[threadIdx.x] = sq;
  __syncthreads();
  for (int off = 128; off > 0; off >>= 1) {
    if (threadIdx.x < off) {
      rs[threadIdx.x] += rs[threadIdx.x + off];
      rq[threadIdx.x] += rq[threadIdx.x + off];
    }
    __syncthreads();
  }
  if (threadIdx.x == 0) {
    const double mean = rs[0] / count;
    const double var  = rq[0] / count - mean * mean;  // biased var
    const double rstd = 1.0 / sqrt(var + 1e-5);
    const double sc = (double)g[c] * rstd;
    scale[c] = (float)sc;
    shift[c] = (float)((double)bta[c] - mean * sc);
  }
}

// ------------- conv1 + BN + ReLU + pool fused (recompute conv) --------------
// thread = one pooled px, all 16 co. grid (49, 64), 256 thr.
__global__ __launch_bounds__(256)
void k_conv1_pool(const float* __restrict__ d, const float* __restrict__ w1,
                  const float* __restrict__ b1, const float* __restrict__ st,
                  float* __restrict__ x1) {
  const int n = blockIdx.y;
  const int s = blockIdx.x * 256 + threadIdx.x;  // < 12544
  const int po = s / 112, qo = s - po * 112;
  float pa[3][3][4];  // rows 2po-1..2po+1, ci, cols 2qo-2..2qo+1
  #pragma unroll
  for (int r = 0; r < 3; ++r) {
    const int ih = 2 * po - 1 + r;
    const bool rv = (unsigned)ih < 224u;
    #pragma unroll
    for (int ci = 0; ci < 3; ++ci) {
      const float* rp = d + ((size_t)(n * 3 + ci) * 224 + ih) * 224;
      float2 a = make_float2(0.f, 0.f), b = make_float2(0.f, 0.f);
      if (rv) {
        if (qo > 0) a = *reinterpret_cast<const float2*>(rp + 2 * qo - 2);
        b = *reinterpret_cast<const float2*>(rp + 2 * qo);
      }
      pa[r][ci][0] = a.x; pa[r][ci][1] = a.y;
      pa[r][ci][2] = b.x; pa[r][ci][3] = b.y;
    }
  }
  #pragma unroll
  for (int co = 0; co < 16; ++co) {
    float wz[3][4];
    #pragma unroll
    for (int ci = 0; ci < 3; ++ci)
      #pragma unroll
      for (int k = 0; k < 4; ++k)
        wz[ci][k] = w1[(co * 3 + ci) * 4 + k];
    const float bias = b1[co];
    float acc[2][2] = {{bias, bias}, {bias, bias}};
    #pragma unroll
    for (int ci = 0; ci < 3; ++ci)
      #pragma unroll
      for (int kh = 0; kh < 2; ++kh)
        #pragma unroll
        for (int kw = 0; kw < 2; ++kw) {
          const float w = wz[ci][kh * 2 + kw];
          #pragma unroll
          for (int dy = 0; dy < 2; ++dy)
            #pragma unroll
            for (int dx = 0; dx < 2; ++dx)
              acc[dy][dx] = fmaf(pa[dy + kh][ci][dx + kw + 1], w, acc[dy][dx]);
        }
    const float sc = st[co], sh = st[16 + co];
    const float v00 = fmaxf(fmaf(acc[0][0], sc, sh), 0.f);
    const float v01 = fmaxf(fmaf(acc[0][1], sc, sh), 0.f);
    const float v10 = fmaxf(fmaf(acc[1][0], sc, sh), 0.f);
    const float v11 = fmaxf(fmaf(acc[1][1], sc, sh), 0.f);
    x1[((size_t)(n * 16 + co) * 112 + po) * 112 + qo] =
        fmaxf(fmaxf(v00, v01), fmaxf(v10, v11));
  }
}

// ------------- 3x3 conv (pad 1) + bias + per-wave stats, generic ------------
// thread = 8 contiguous px in one row, 8 output channels (acc[8][8]).
// grid (7 row-tiles, CO_TOT/8 groups, 64 n), block = ROWS*RUNS threads.
template<int CI, int CO_TOT, int H, int ROWS, int RUNS>
__global__ __launch_bounds__(ROWS * RUNS)
void k_conv3x3(const float* __restrict__ xin, const float* __restrict__ wg,
               const float* __restrict__ bg, float* __restrict__ yout,
               float* __restrict__ part) {
  constexpr int LW = RUNS * 8;       // lds width (floats)
  constexpr int VRUNS = H / 8;       // valid col-runs
  constexpr int NW = (ROWS * RUNS) / 64;
  constexpr int SLOTS = (ROWS + 2) * (LW / 4);  // float4 staging slots
  constexpr int PP = 64 * 7 * NW;    // partials per channel
  const int tY = blockIdx.x, cog = blockIdx.y, n = blockIdx.z;
  const int t = threadIdx.x;
  const int r = t / RUNS, u = t % RUNS;
  __shared__ __align__(16) float tile[ROWS + 2][LW];
  float acc[8][8];
  {
    float bv[8];
    #pragma unroll
    for (int o = 0; o < 8; ++o) bv[o] = bg[cog * 8 + o];
    #pragma unroll
    for (int p = 0; p < 8; ++p)
      #pragma unroll
      for (int o = 0; o < 8; ++o) acc[p][o] = bv[o];
  }
  const int oh = tY * ROWS + r;
  const int c0 = 8 * u;
  for (int ci = 0; ci < CI; ++ci) {
    const float* src = xin + ((size_t)(n * CI + ci) * H) * H;
    for (int idx = t; idx < SLOTS; idx += ROWS * RUNS) {
      const int rr = idx / (LW / 4);
      const int j4 = (idx - rr * (LW / 4)) * 4;
      const int ih = tY * ROWS + rr - 1;
      const int iw = j4 - 4;
      float4 v = make_float4(0.f, 0.f, 0.f, 0.f);
      if ((unsigned)ih < (unsigned)H && iw >= 0 && iw <= H - 4)
        v = ldg4(src + (size_t)ih * H + iw);
      *reinterpret_cast<float4*>(&tile[rr][j4]) = v;
    }
    __syncthreads();
    if (u < VRUNS) {
      #pragma unroll
      for (int kh = 0; kh < 3; ++kh) {
        float va[16];
        #pragma unroll
        for (int ch = 0; ch < 4; ++ch) {
          const float4 v = *reinterpret_cast<const float4*>(&tile[r + kh][c0 + 4 * ch]);
          va[4 * ch + 0] = v.x; va[4 * ch + 1] = v.y;
          va[4 * ch + 2] = v.z; va[4 * ch + 3] = v.w;
        }
        #pragma unroll
        for (int kw = 0; kw < 3; ++kw) {
          float wv[8];
          #pragma unroll
          for (int o = 0; o < 8; ++o)
            wv[o] = wg[((size_t)(cog * 8 + o) * CI + ci) * 9 + kh * 3 + kw];  // uniform
          #pragma unroll
          for (int p = 0; p < 8; ++p) {
            const float a = va[p + kw + 3];
            #pragma unroll
            for (int o = 0; o < 8; ++o) acc[p][o] = fmaf(a, wv[o], acc[p][o]);
          }
        }
      }
    }
    __syncthreads();
  }
  float sum[8], sq[8];
  #pragma unroll
  for (int o = 0; o < 8; ++o) { sum[o] = 0.f; sq[o] = 0.f; }
  if (u < VRUNS) {
    #pragma unroll
    for (int o = 0; o < 8; ++o) {
      float* dst = yout + ((size_t)(n * CO_TOT + cog * 8 + o) * H + oh) * H + c0;
      *reinterpret_cast<float4*>(dst) =
          make_float4(acc[0][o], acc[1][o], acc[2][o], acc[3][o]);
      *reinterpret_cast<float4*>(dst + 4) =
          make_float4(acc[4][o], acc[5][o], acc[6][o], acc[7][o]);
      #pragma unroll
      for (int p = 0; p < 8; ++p) {
        sum[o] += acc[p][o];
        sq[o] = fmaf(acc[p][o], acc[p][o], sq[o]);
      }
    }
  }
  #pragma unroll
  for (int m = 1; m < 64; m <<= 1) {
    #pragma unroll
    for (int o = 0; o < 8; ++o) {
      sum[o] += __shfl_xor(sum[o], m);
      sq[o]  += __shfl_xor(sq[o], m);
    }
  }
  if ((t & 63) == 0) {
    const int p = (n * 7 + tY) * NW + (t >> 6);
    #pragma unroll
    for (int o = 0; o < 8; ++o) {
      part[(size_t)((cog * 8 + o) * 2 + 0) * PP + p] = sum[o];
      part[(size_t)((cog * 8 + o) * 2 + 1) * PP + p] = sq[o];
    }
  }
}

// ------------- BN + ReLU + maxpool2 (elementwise), 2 pooled px/thread -------
__global__ __launch_bounds__(256)
void k_bnpool(const float* __restrict__ y, const float* __restrict__ scale,
              const float* __restrict__ shift, float* __restrict__ x,
              int C, int H) {
  const int P = H / 2, Q = P / 2;
  const int idx = blockIdx.x * 256 + threadIdx.x;
  const int total = 64 * C * P * Q;
  if (idx >= total) return;
  const int q2 = idx % Q;
  int tmp = idx / Q;
  const int po = tmp % P; tmp /= P;
  const int c = tmp % C;
  const int n = tmp / C;
  const float* base = y + ((size_t)(n * C + c) * H + 2 * po) * H + 4 * q2;
  const float4 a = ldg4(base);
  const float4 b = ldg4(base + H);
  const float sc = scale[c], sh = shift[c];
  const float v0 = fmaxf(fmaxf(fmaxf(fmaf(a.x, sc, sh), fmaf(a.y, sc, sh)),
                               fmaxf(fmaf(b.x, sc, sh), fmaf(b.y, sc, sh))), 0.f);
  const float v1 = fmaxf(fmaxf(fmaxf(fmaf(a.z, sc, sh), fmaf(a.w, sc, sh)),
                               fmaxf(fmaf(b.z, sc, sh), fmaf(b.w, sc, sh))), 0.f);
  float2 o; o.x = v0; o.y = v1;
  *reinterpret_cast<float2*>(x + ((size_t)(n * C + c) * P + po) * P + 2 * q2) = o;
}

// ------------- fc1: [64,50176] @ [256,50176]^T, K-split partials ------------
// grid (56 ksplit, 4 ntile), 256 thr; per block M=64, N=64, K=896 (14x64).
__global__ __launch_bounds__(256)
void k_fc1(const float* __restrict__ x3, const float* __restrict__ w,
           float* __restrict__ partial) {
  const int ks = blockIdx.x, nt = blockIdx.y;
  const int t = threadIdx.x;
  const int tm = t >> 4, tn = t & 15;
  __shared__ __align__(16) float xs[64][68];
  __shared__ __align__(16) float wsx[64][68];
  float acc[4][4];
  #pragma unroll
  for (int i = 0; i < 4; ++i)
    #pragma unroll
    for (int j = 0; j < 4; ++j) acc[i][j] = 0.f;
  for (int ch = 0; ch < 14; ++ch) {
    const int kb = ks * 896 + ch * 64;
    #pragma unroll
    for (int i = 0; i < 4; ++i) {
      const int idx = t + 256 * i;  // 0..1023
      const int row = idx >> 4, c4 = (idx & 15) * 4;
      *reinterpret_cast<float4*>(&xs[row][c4]) =
          ldg4(x3 + (size_t)row * 50176 + kb + c4);
      *reinterpret_cast<float4*>(&wsx[row][c4]) =
          ldg4(w + (size_t)(nt * 64 + row) * 50176 + kb + c4);
    }
    __syncthreads();
    #pragma unroll
    for (int k4 = 0; k4 < 16; ++k4) {
      float4 xr[4], wr[4];
      #pragma unroll
      for (int i = 0; i < 4; ++i)
        xr[i] = *reinterpret_cast<const float4*>(&xs[tm + 16 * i][k4 * 4]);
      #pragma unroll
      for (int j = 0; j < 4; ++j)
        wr[j] = *reinterpret_cast<const float4*>(&wsx[tn * 4 + j][k4 * 4]);
      #pragma unroll
      for (int i = 0; i < 4; ++i)
        #pragma unroll
        for (int j = 0; j < 4; ++j) {
          float a = acc[i][j];
          a = fmaf(xr[i].x, wr[j].x, a);
          a = fmaf(xr[i].y, wr[j].y, a);
          a = fmaf(xr[i].z, wr[j].z, a);
          a = fmaf(xr[i].w, wr[j].w, a);
          acc[i][j] = a;
        }
    }
    __syncthreads();
  }
  #pragma unroll
  for (int j = 0; j < 4; ++j)
    #pragma unroll
    for (int i = 0; i < 4; ++i)
      partial[(size_t)ks * 16384 + (nt * 64 + tn * 4 + j) * 64 + tm + 16 * i] =
          acc[i][j];
}

__global__ __launch_bounds__(256)
void k_fc1_reduce(const float* __restrict__ partial, const float* __restrict__ b1f,
                  float* __restrict__ h1) {
  const int idx = blockIdx.x * 256 + threadIdx.x;  // 16384 ; idx = n*64+m
  const int nn = idx >> 6, m = idx & 63;
  float s = b1f[nn];
  for (int k = 0; k < 56; ++k) s += partial[(size_t)k * 16384 + idx];
  h1[(size_t)m * 256 + nn] = fmaxf(s, 0.f);
}

__global__ __launch_bounds__(320)
void k_fc2(const float* __restrict__ h1, const float* __restrict__ w2f,
           const float* __restrict__ b2f, float* __restrict__ out) {
  const int t = threadIdx.x;
  const int m = t / 5, o = t - m * 5;
  float s = b2f[o];
  const float* hr = h1 + (size_t)m * 256;
  const float* wr = w2f + (size_t)o * 256;
  for (int j = 0; j < 256; j += 4) {
    const float4 h = ldg4(hr + j);
    const float4 w = ldg4(wr + j);
    s = fmaf(h.x, w.x, s); s = fmaf(h.y, w.y, s);
    s = fmaf(h.z, w.z, s); s = fmaf(h.w, w.w, s);
  }
  out[m * 5 + o] = s;
}

// ---------------------------------------------------------------------------
extern "C" void kernel_launch(void* const* d_in, const int* in_sizes, int n_in,
                              void* d_out, int out_size, void* d_ws, size_t ws_size,
                              hipStream_t stream) {
  (void)in_sizes; (void)n_in; (void)out_size; (void)ws_size;
  const float* d   = (const float*)d_in[0];
  const float* w1  = (const float*)d_in[1];
  const float* b1  = (const float*)d_in[2];
  const float* g1  = (const float*)d_in[3];
  const float* be1 = (const float*)d_in[4];
  const float* w2  = (const float*)d_in[5];
  const float* b2  = (const float*)d_in[6];
  const float* g2  = (const float*)d_in[7];
  const float* be2 = (const float*)d_in[8];
  const float* w3  = (const float*)d_in[9];
  const float* b3  = (const float*)d_in[10];
  const float* g3  = (const float*)d_in[11];
  const float* be3 = (const float*)d_in[12];
  const float* fw1 = (const float*)d_in[13];
  const float* fb1 = (const float*)d_in[14];
  const float* fw2 = (const float*)d_in[15];
  const float* fb2 = (const float*)d_in[16];
  float* out = (float*)d_out;
  float* ws  = (float*)d_ws;

  float* x1  = ws + WS_X1;
  float* y2  = ws + WS_Y2;
  float* x2  = ws + WS_X2;
  float* y3  = ws + WS_Y2;  // alias (y2 dead)
  float* x3  = ws + WS_X1;  // alias (x1 dead)
  float* p1  = ws + WS_P1;
  float* p2  = ws + WS_P2;
  float* p3  = ws + WS_P3;
  float* st  = ws + WS_ST;
  float* fcp = ws + WS_FCP;
  float* h1  = ws + WS_H1;

  // layer 1
  k_conv1_stats<<<dim3(26, 16, 64), 256, 0, stream>>>(d, w1, b1, p1);
  k_finalize<<<16, 256, 0, stream>>>(p1, 6656, 3240000.0, g1, be1, st + 0, st + 16);
  k_conv1_pool<<<dim3(49, 64), 256, 0, stream>>>(d, w1, b1, st, x1);
  // layer 2
  k_conv3x3<16, 32, 112, 16, 16><<<dim3(7, 4, 64), 256, 0, stream>>>(x1, w2, b2, y2, p2);
  k_finalize<<<32, 256, 0, stream>>>(p2, 1792, 802816.0, g2, be2, st + 32, st + 64);
  k_bnpool<<<12544, 256, 0, stream>>>(y2, st + 32, st + 64, x2, 32, 112);
  // layer 3
  k_conv3x3<32, 64, 56, 8, 8><<<dim3(7, 8, 64), 64, 0, stream>>>(x2, w3, b3, y3, p3);
  k_finalize<<<64, 256, 0, stream>>>(p3, 448, 200704.0, g3, be3, st + 96, st + 160);
  k_bnpool<<<6272, 256, 0, stream>>>(y3, st + 96, st + 160, x3, 64, 56);
  // fc
  k_fc1<<<dim3(56, 4), 256, 0, stream>>>(x3, fw1, fcp);
  k_fc1_reduce<<<64, 256, 0, stream>>>(fcp, fb1, h1);
  k_fc2<<<1, 320, 0, stream>>>(h1, fw2, fb2, out);
}

// Round 3
// 284.419 us; speedup vs baseline: 2.1691x; 2.1691x over previous
//
#include <hip/hip_runtime.h>
#include <cstdint>
#include <cstddef>

// ---------------------------------------------------------------------------
// Plant_Identifier CNN forward.
// conv1 fp32 (stats pass + fused pool pass, NHWC bf16 out)
// conv2/conv3: bf16 MFMA implicit-GEMM (16x16x32), fused per-wave BN stats
// bnpool: bf16 elementwise; bnpool3 fuses NHWC->NCHW transpose for fc1
// fc1/fc2: fp32 (fc1 weights are the 51MB stream; x side bf16)
// All reductions deterministic (two-stage partials).
// R3 fix: WS_P1 previously overlapped wt3 (18432 bf16 = 9216 float slots,
// not 4608) -> conv1_stats clobbered conv3 weights for co 32..63.
// ---------------------------------------------------------------------------

typedef __attribute__((ext_vector_type(8))) short sh8_t;   // 8 x bf16
typedef __attribute__((ext_vector_type(4))) float f4_t;    // mfma acc
typedef unsigned short u16;
typedef unsigned int u32;

// workspace layout (float units)
#define WS_X1   ((size_t)0)          // x1  bf16 [64,112,112,16] -> 6,422,528 slots
#define WS_Y2   ((size_t)6422528)    // y2  bf16 [64,112,112,32] (12,845,056); later y3 [64,56,56,64]
#define WS_X2   ((size_t)19267584)   // x2  bf16 [64,56,56,32] (3,211,264)
#define WS_X3T  ((size_t)22478848)   // x3t bf16 [64,64,28,28] (1,605,632)
#define WS_WT2  ((size_t)24084480)   // wt2 bf16 [32][3][4][16] (3,072 slots)
#define WS_WT3  ((size_t)24087552)   // wt3 bf16 [64][3][3][32] (9,216 slots)
#define WS_P1   ((size_t)24096768)   // 16*2*1664  = 53,248
#define WS_P2   ((size_t)24150016)   // 32*2*12544 = 802,816
#define WS_P3   ((size_t)24952832)   // 64*2*3584  = 458,752
#define WS_ST   ((size_t)25411584)   // 224: scale1(16),shift1(16),scale2(32),shift2(32),scale3(64),shift3(64)
#define WS_FCP  ((size_t)25411808)   // 56*16384 = 917,504
#define WS_H1   ((size_t)26329312)   // 16,384
// total 26,345,696 floats = 105.4 MB

static __device__ __forceinline__ float4 ldg4(const float* p) {
  return *reinterpret_cast<const float4*>(p);
}
static __device__ __forceinline__ float bf2f(u16 u) {
  union { u32 i; float f; } c; c.i = ((u32)u) << 16; return c.f;
}
static __device__ __forceinline__ u16 f2bf(float f) {
  union { float f; u32 i; } c; c.f = f;
  const u32 x = c.i;
  return (u16)((x + 0x7fffu + ((x >> 16) & 1u)) >> 16);   // RNE
}

// ---------------- weight prep: fp32 OIHW -> bf16 co-major K layouts ---------
__global__ __launch_bounds__(256)
void k_prep_w(const float* __restrict__ w2, const float* __restrict__ w3,
              u16* __restrict__ wt2, u16* __restrict__ wt3) {
  const int t = blockIdx.x * 256 + threadIdx.x;  // 24576 total
  if (t < 6144) {  // wt2 [co32][kh3][kwp4][ci16], kw=3 zero-padded
    const int ci = t & 15, kwp = (t >> 4) & 3, kh = (t >> 6) % 3, co = t / 192;
    float v = 0.f;
    if (kwp < 3) v = w2[((co * 16 + ci) * 3 + kh) * 3 + kwp];
    wt2[t] = f2bf(v);
  } else {         // wt3 [co64][kh3][kw3][ci32]
    const int u = t - 6144;
    const int ci = u & 31, kw = (u >> 5) % 3, kh = (u / 96) % 3, co = u / 288;
    wt3[u] = f2bf(w3[((co * 32 + ci) * 3 + kh) * 3 + kw]);
  }
}

// ---------------- conv1 stats pass (recompute, all 16 co per thread) --------
// grid (26, 64), 256 thr; thread = 8-px run of the 225x225 pre-pool map.
__global__ __launch_bounds__(256)
void k_conv1_stats(const float* __restrict__ d, const float* __restrict__ w1,
                   const float* __restrict__ b1, float* __restrict__ part) {
  const int n = blockIdx.y;
  const int t = threadIdx.x;
  const int slot = blockIdx.x * 256 + t;  // over 225*29 = 6525
  const int oh = slot / 29, q = slot - oh * 29;
  float sum[16], sq[16];
  #pragma unroll
  for (int co = 0; co < 16; ++co) { sum[co] = 0.f; sq[co] = 0.f; }
  if (slot < 6525) {
    float pa[2][3][12];  // rows {oh-1, oh}, 3 ci, cols 8q-4..8q+7
    #pragma unroll
    for (int r = 0; r < 2; ++r) {
      const int ih = oh - 1 + r;
      const bool rv = (unsigned)ih < 224u;
      #pragma unroll
      for (int ci = 0; ci < 3; ++ci) {
        const float* rp = d + ((size_t)(n * 3 + ci) * 224 + ih) * 224;
        #pragma unroll
        for (int ch = 0; ch < 3; ++ch) {
          const int c0 = 8 * q - 4 + 4 * ch;
          float4 v = make_float4(0.f, 0.f, 0.f, 0.f);
          if (rv && c0 >= 0 && c0 <= 220) v = ldg4(rp + c0);
          pa[r][ci][ch * 4 + 0] = v.x; pa[r][ci][ch * 4 + 1] = v.y;
          pa[r][ci][ch * 4 + 2] = v.z; pa[r][ci][ch * 4 + 3] = v.w;
        }
      }
    }
    #pragma unroll
    for (int co = 0; co < 16; ++co) {
      float wz[12];
      #pragma unroll
      for (int z = 0; z < 12; ++z) wz[z] = w1[co * 12 + z];
      const float bias = b1[co];
      #pragma unroll
      for (int p = 0; p < 8; ++p) {
        if (8 * q + p <= 224) {
          float v = bias;
          #pragma unroll
          for (int ci = 0; ci < 3; ++ci)
            #pragma unroll
            for (int kh = 0; kh < 2; ++kh)
              #pragma unroll
              for (int kw = 0; kw < 2; ++kw)
                v = fmaf(pa[kh][ci][p + kw + 3], wz[ci * 4 + kh * 2 + kw], v);
          sum[co] += v;
          sq[co] = fmaf(v, v, sq[co]);
        }
      }
    }
  }
  // block tree-reduce: red[32][257]
  __shared__ float red[32][257];
  #pragma unroll
  for (int co = 0; co < 16; ++co) { red[co][t] = sum[co]; red[16 + co][t] = sq[co]; }
  __syncthreads();
  for (int off = 128; off > 0; off >>= 1) {
    if (t < off) {
      #pragma unroll
      for (int z = 0; z < 32; ++z) red[z][t] += red[z][t + off];
    }
    __syncthreads();
  }
  if (t < 16) {
    const int p = n * 26 + blockIdx.x;  // P1 = 1664
    part[(t * 2 + 0) * 1664 + p] = red[t][0];
    part[(t * 2 + 1) * 1664 + p] = red[16 + t][0];
  }
}

// ------------- finalize: partials -> per-channel scale/shift ----------------
__global__ __launch_bounds__(256)
void k_finalize(const float* __restrict__ part, int P, double count,
                const float* __restrict__ g, const float* __restrict__ bta,
                float* __restrict__ scale, float* __restrict__ shift) {
  const int c = blockIdx.x;
  double s = 0.0, sq = 0.0;
  for (int i = threadIdx.x; i < P; i += 256) {
    s  += (double)part[(size_t)(c * 2 + 0) * P + i];
    sq += (double)part[(size_t)(c * 2 + 1) * P + i];
  }
  __shared__ double rs[256], rq[256];
  rs[threadIdx.x] = s; rq[threadIdx.x] = sq;
  __syncthreads();
  for (int off = 128; off > 0; off >>= 1) {
    if (threadIdx.x < off) {
      rs[threadIdx.x] += rs[threadIdx.x + off];
      rq[threadIdx.x] += rq[threadIdx.x + off];
    }
    __syncthreads();
  }
  if (threadIdx.x == 0) {
    const double mean = rs[0] / count;
    const double var  = rq[0] / count - mean * mean;
    const double rstd = 1.0 / sqrt(var + 1e-5);
    const double sc = (double)g[c] * rstd;
    scale[c] = (float)sc;
    shift[c] = (float)((double)bta[c] - mean * sc);
  }
}

// ------------- conv1 + BN + ReLU + pool fused -> x1 NHWC bf16 ---------------
__global__ __launch_bounds__(256)
void k_conv1_pool(const float* __restrict__ d, const float* __restrict__ w1,
                  const float* __restrict__ b1, const float* __restrict__ st,
                  u16* __restrict__ x1) {
  const int n = blockIdx.y;
  const int s = blockIdx.x * 256 + threadIdx.x;  // 12544
  const int po = s / 112, qo = s - po * 112;
  float pa[3][3][4];
  #pragma unroll
  for (int r = 0; r < 3; ++r) {
    const int ih = 2 * po - 1 + r;
    const bool rv = (unsigned)ih < 224u;
    #pragma unroll
    for (int ci = 0; ci < 3; ++ci) {
      const float* rp = d + ((size_t)(n * 3 + ci) * 224 + ih) * 224;
      float2 a = make_float2(0.f, 0.f), b = make_float2(0.f, 0.f);
      if (rv) {
        if (qo > 0) a = *reinterpret_cast<const float2*>(rp + 2 * qo - 2);
        b = *reinterpret_cast<const float2*>(rp + 2 * qo);
      }
      pa[r][ci][0] = a.x; pa[r][ci][1] = a.y;
      pa[r][ci][2] = b.x; pa[r][ci][3] = b.y;
    }
  }
  u16 outv[16];
  #pragma unroll
  for (int co = 0; co < 16; ++co) {
    const float bias = b1[co];
    float acc[2][2] = {{bias, bias}, {bias, bias}};
    #pragma unroll
    for (int ci = 0; ci < 3; ++ci)
      #pragma unroll
      for (int kh = 0; kh < 2; ++kh)
        #pragma unroll
        for (int kw = 0; kw < 2; ++kw) {
          const float w = w1[co * 12 + ci * 4 + kh * 2 + kw];
          #pragma unroll
          for (int dy = 0; dy < 2; ++dy)
            #pragma unroll
            for (int dx = 0; dx < 2; ++dx)
              acc[dy][dx] = fmaf(pa[dy + kh][ci][dx + kw + 1], w, acc[dy][dx]);
        }
    const float sc = st[co], sh = st[16 + co];
    const float v00 = fmaxf(fmaf(acc[0][0], sc, sh), 0.f);
    const float v01 = fmaxf(fmaf(acc[0][1], sc, sh), 0.f);
    const float v10 = fmaxf(fmaf(acc[1][0], sc, sh), 0.f);
    const float v11 = fmaxf(fmaf(acc[1][1], sc, sh), 0.f);
    outv[co] = f2bf(fmaxf(fmaxf(v00, v01), fmaxf(v10, v11)));
  }
  u16* o = x1 + ((size_t)((n * 112 + po) * 112 + qo)) * 16;
  u32 pk[8];
  #pragma unroll
  for (int k = 0; k < 8; ++k) pk[k] = (u32)outv[2 * k] | ((u32)outv[2 * k + 1] << 16);
  *reinterpret_cast<int4*>(o)     = make_int4(pk[0], pk[1], pk[2], pk[3]);
  *reinterpret_cast<int4*>(o + 8) = make_int4(pk[4], pk[5], pk[6], pk[7]);
}

// ------------- conv2: bf16 MFMA, CI=16 CO=32 H=112, kw padded to 4 ----------
// grid (7 owt, 7 strip, 64 n), 256 thr. wave = 4 oh rows x 16 ow x 32 co.
__global__ __launch_bounds__(256)
void k_conv2(const u16* __restrict__ x1, const u16* __restrict__ wt2,
             const float* __restrict__ b2, u16* __restrict__ y2,
             float* __restrict__ part) {
  const int ow0 = blockIdx.x * 16, oh0 = blockIdx.y * 16, n = blockIdx.z;
  const int t = threadIdx.x, lane = t & 63, wv = t >> 6;
  const int g = lane >> 4, li = lane & 15;
  __shared__ __align__(16) unsigned char tile[18 * 640];  // rows x 20px x 32B
  // stage x1 tile: rows oh0-1..oh0+16, cols ow0-1..ow0+18 (zero halo)
  for (int idx = t; idx < 720; idx += 256) {
    const int rr = idx / 40, rem = idx - rr * 40, p = rem >> 1, c = rem & 1;
    const int ih = oh0 - 1 + rr, iw = ow0 - 1 + p;
    int4 v = make_int4(0, 0, 0, 0);
    if ((unsigned)ih < 112u && (unsigned)iw < 112u)
      v = *reinterpret_cast<const int4*>(x1 + ((size_t)((n * 112 + ih) * 112 + iw) * 16 + c * 8));
    *reinterpret_cast<int4*>(tile + ((rr * 640 + p * 32 + c * 16) ^ (((p >> 2) & 1) << 4))) = v;
  }
  // weights: W[cot][kh][m], k64 = kw*16+ci, kw=2m+(g>>1), ci=8(g&1)+j
  sh8_t W[2][3][2];
  #pragma unroll
  for (int cot = 0; cot < 2; ++cot)
    #pragma unroll
    for (int kh = 0; kh < 3; ++kh)
      #pragma unroll
      for (int m = 0; m < 2; ++m)
        W[cot][kh][m] = *reinterpret_cast<const sh8_t*>(
            wt2 + ((cot * 16 + li) * 192 + kh * 64 + m * 32 + g * 8));
  f4_t acc[4][2];
  #pragma unroll
  for (int r = 0; r < 4; ++r) { acc[r][0] = (f4_t)0.f; acc[r][1] = (f4_t)0.f; }
  __syncthreads();
  const int rowb = 4 * wv;
  #pragma unroll
  for (int ihr = 0; ihr < 6; ++ihr) {
    const int row = rowb + ihr;
    #pragma unroll
    for (int m = 0; m < 2; ++m) {
      const int p = li + 2 * m + (g >> 1);
      const sh8_t B = *reinterpret_cast<const sh8_t*>(
          tile + ((row * 640 + p * 32 + (g & 1) * 16) ^ (((p >> 2) & 1) << 4)));
      #pragma unroll
      for (int kh = 0; kh < 3; ++kh) {
        const int r = ihr - kh;
        if (r >= 0 && r < 4) {
          acc[r][0] = __builtin_amdgcn_mfma_f32_16x16x32_bf16(W[0][kh][m], B, acc[r][0], 0, 0, 0);
          acc[r][1] = __builtin_amdgcn_mfma_f32_16x16x32_bf16(W[1][kh][m], B, acc[r][1], 0, 0, 0);
        }
      }
    }
  }
  // epilogue: bias, store bf16, fused stats. lane co = cot*16 + 4g + j
  f4_t bias[2], ssum[2], ssq[2];
  bias[0] = *reinterpret_cast<const f4_t*>(b2 + 4 * g);
  bias[1] = *reinterpret_cast<const f4_t*>(b2 + 16 + 4 * g);
  ssum[0] = (f4_t)0.f; ssum[1] = (f4_t)0.f; ssq[0] = (f4_t)0.f; ssq[1] = (f4_t)0.f;
  const int ohb = oh0 + 4 * wv;
  #pragma unroll
  for (int r = 0; r < 4; ++r)
    #pragma unroll
    for (int cot = 0; cot < 2; ++cot) {
      const f4_t y = acc[r][cot] + bias[cot];
      ssum[cot] += y; ssq[cot] += y * y;
      const size_t off = ((size_t)((n * 112 + ohb + r) * 112 + ow0 + li)) * 32 + cot * 16 + 4 * g;
      uint2 pk;
      pk.x = (u32)f2bf(y[0]) | ((u32)f2bf(y[1]) << 16);
      pk.y = (u32)f2bf(y[2]) | ((u32)f2bf(y[3]) << 16);
      *reinterpret_cast<uint2*>(y2 + off) = pk;
    }
  #pragma unroll
  for (int msk = 1; msk < 16; msk <<= 1)
    #pragma unroll
    for (int cot = 0; cot < 2; ++cot)
      #pragma unroll
      for (int j = 0; j < 4; ++j) {
        ssum[cot][j] += __shfl_xor(ssum[cot][j], msk);
        ssq[cot][j]  += __shfl_xor(ssq[cot][j], msk);
      }
  if (li == 0) {
    const int slot = (((n * 7 + (int)blockIdx.y) * 7 + (int)blockIdx.x)) * 4 + wv;  // 12544
    #pragma unroll
    for (int cot = 0; cot < 2; ++cot)
      #pragma unroll
      for (int j = 0; j < 4; ++j) {
        const int co = cot * 16 + 4 * g + j;
        part[(size_t)(co * 2 + 0) * 12544 + slot] = ssum[cot][j];
        part[(size_t)(co * 2 + 1) * 12544 + slot] = ssq[cot][j];
      }
  }
}

// ------------- conv3: bf16 MFMA, CI=32 CO=64 H=56 ---------------------------
// grid (4 owt, 7 strip, 64 n), 256 thr. wave = (rowhalf, cohalf): 4 rows x 32 co.
__global__ __launch_bounds__(256)
void k_conv3(const u16* __restrict__ x2, const u16* __restrict__ wt3,
             const float* __restrict__ b3, u16* __restrict__ y3,
             float* __restrict__ part) {
  const int ow0 = blockIdx.x * 16, oh0 = blockIdx.y * 8, n = blockIdx.z;
  const int t = threadIdx.x, lane = t & 63, wv = t >> 6;
  const int rh = wv & 1, ch = wv >> 1;
  const int g = lane >> 4, li = lane & 15;
  __shared__ __align__(16) unsigned char tile[10 * 1152];  // rows x 18px x 64B
  for (int idx = t; idx < 720; idx += 256) {
    const int rr = idx / 72, rem = idx - rr * 72, p = rem >> 2, c = rem & 3;
    const int ih = oh0 - 1 + rr, iw = ow0 - 1 + p;
    int4 v = make_int4(0, 0, 0, 0);
    if ((unsigned)ih < 56u && (unsigned)iw < 56u)
      v = *reinterpret_cast<const int4*>(x2 + ((size_t)((n * 56 + ih) * 56 + iw) * 32 + c * 8));
    *reinterpret_cast<int4*>(tile + ((rr * 1152 + p * 64 + c * 16) ^ (((p >> 1) & 3) << 4))) = v;
  }
  sh8_t W[2][3][3];
  #pragma unroll
  for (int c2 = 0; c2 < 2; ++c2)
    #pragma unroll
    for (int kh = 0; kh < 3; ++kh)
      #pragma unroll
      for (int kw = 0; kw < 3; ++kw)
        W[c2][kh][kw] = *reinterpret_cast<const sh8_t*>(
            wt3 + ((size_t)(ch * 32 + c2 * 16 + li) * 288 + (kh * 3 + kw) * 32 + g * 8));
  f4_t acc[4][2];
  #pragma unroll
  for (int r = 0; r < 4; ++r) { acc[r][0] = (f4_t)0.f; acc[r][1] = (f4_t)0.f; }
  __syncthreads();
  const int rowb = 4 * rh;
  #pragma unroll
  for (int ihr = 0; ihr < 6; ++ihr) {
    const int row = rowb + ihr;
    #pragma unroll
    for (int kw = 0; kw < 3; ++kw) {
      const int p = li + kw;
      const sh8_t B = *reinterpret_cast<const sh8_t*>(
          tile + ((row * 1152 + p * 64 + g * 16) ^ (((p >> 1) & 3) << 4)));
      #pragma unroll
      for (int kh = 0; kh < 3; ++kh) {
        const int r = ihr - kh;
        if (r >= 0 && r < 4) {
          acc[r][0] = __builtin_amdgcn_mfma_f32_16x16x32_bf16(W[0][kh][kw], B, acc[r][0], 0, 0, 0);
          acc[r][1] = __builtin_amdgcn_mfma_f32_16x16x32_bf16(W[1][kh][kw], B, acc[r][1], 0, 0, 0);
        }
      }
    }
  }
  const int ow = ow0 + li;
  const bool valid = ow < 56;
  f4_t bias[2], ssum[2], ssq[2];
  bias[0] = *reinterpret_cast<const f4_t*>(b3 + ch * 32 + 4 * g);
  bias[1] = *reinterpret_cast<const f4_t*>(b3 + ch * 32 + 16 + 4 * g);
  ssum[0] = (f4_t)0.f; ssum[1] = (f4_t)0.f; ssq[0] = (f4_t)0.f; ssq[1] = (f4_t)0.f;
  const int ohb = oh0 + 4 * rh;
  #pragma unroll
  for (int r = 0; r < 4; ++r)
    #pragma unroll
    for (int c2 = 0; c2 < 2; ++c2) {
      const f4_t y = acc[r][c2] + bias[c2];
      if (valid) {
        ssum[c2] += y; ssq[c2] += y * y;
        const size_t off = ((size_t)((n * 56 + ohb + r) * 56 + ow)) * 64 + ch * 32 + c2 * 16 + 4 * g;
        uint2 pk;
        pk.x = (u32)f2bf(y[0]) | ((u32)f2bf(y[1]) << 16);
        pk.y = (u32)f2bf(y[2]) | ((u32)f2bf(y[3]) << 16);
        *reinterpret_cast<uint2*>(y3 + off) = pk;
      }
    }
  #pragma unroll
  for (int msk = 1; msk < 16; msk <<= 1)
    #pragma unroll
    for (int c2 = 0; c2 < 2; ++c2)
      #pragma unroll
      for (int j = 0; j < 4; ++j) {
        ssum[c2][j] += __shfl_xor(ssum[c2][j], msk);
        ssq[c2][j]  += __shfl_xor(ssq[c2][j], msk);
      }
  if (li == 0) {
    const int slot = (((n * 7 + (int)blockIdx.y) * 4 + (int)blockIdx.x)) * 2 + rh;  // 3584
    #pragma unroll
    for (int c2 = 0; c2 < 2; ++c2)
      #pragma unroll
      for (int j = 0; j < 4; ++j) {
        const int co = ch * 32 + c2 * 16 + 4 * g + j;
        part[(size_t)(co * 2 + 0) * 3584 + slot] = ssum[c2][j];
        part[(size_t)(co * 2 + 1) * 3584 + slot] = ssq[c2][j];
      }
  }
}

// ------------- bnpool2: y2 bf16 NHWC -> x2 bf16 NHWC ------------------------
__global__ __launch_bounds__(256)
void k_bnpool2(const u16* __restrict__ y2, const float* __restrict__ scale,
               const float* __restrict__ shift, u16* __restrict__ x2) {
  const int idx = blockIdx.x * 256 + threadIdx.x;  // 802816
  const int cg = idx & 3;
  int rest = idx >> 2;
  const int qo = rest % 56; rest /= 56;
  const int po = rest % 56;
  const int n = rest / 56;
  const size_t base = ((size_t)((n * 112 + 2 * po) * 112 + 2 * qo)) * 32 + cg * 8;
  const int4 r00 = *reinterpret_cast<const int4*>(y2 + base);
  const int4 r01 = *reinterpret_cast<const int4*>(y2 + base + 32);
  const int4 r10 = *reinterpret_cast<const int4*>(y2 + base + 112 * 32);
  const int4 r11 = *reinterpret_cast<const int4*>(y2 + base + 112 * 32 + 32);
  const u32* a = reinterpret_cast<const u32*>(&r00);
  const u32* b = reinterpret_cast<const u32*>(&r01);
  const u32* c = reinterpret_cast<const u32*>(&r10);
  const u32* e = reinterpret_cast<const u32*>(&r11);
  u16 outv[8];
  #pragma unroll
  for (int j = 0; j < 8; ++j) {
    const int dw = j >> 1, hs = (j & 1) * 16;
    const float sc = scale[cg * 8 + j], sh = shift[cg * 8 + j];
    const float v0 = fmaf(bf2f((u16)(a[dw] >> hs)), sc, sh);
    const float v1 = fmaf(bf2f((u16)(b[dw] >> hs)), sc, sh);
    const float v2 = fmaf(bf2f((u16)(c[dw] >> hs)), sc, sh);
    const float v3 = fmaf(bf2f((u16)(e[dw] >> hs)), sc, sh);
    outv[j] = f2bf(fmaxf(fmaxf(fmaxf(v0, v1), fmaxf(v2, v3)), 0.f));
  }
  u32 pk[4];
  #pragma unroll
  for (int k = 0; k < 4; ++k) pk[k] = (u32)outv[2 * k] | ((u32)outv[2 * k + 1] << 16);
  *reinterpret_cast<int4*>(x2 + ((size_t)((n * 56 + po) * 56 + qo)) * 32 + cg * 8) =
      make_int4(pk[0], pk[1], pk[2], pk[3]);
}

// ------------- bnpool3: y3 bf16 NHWC -> x3t bf16 NCHW (fc1 order) -----------
// grid (7, 64), 256 thr: thread = (c 0..63, po-quarter 0..3), full qo row.
__global__ __launch_bounds__(256)
void k_bnpool3(const u16* __restrict__ y3, const float* __restrict__ scale,
               const float* __restrict__ shift, u16* __restrict__ x3t) {
  const int n = blockIdx.y;
  const int c = threadIdx.x & 63, pq = threadIdx.x >> 6;
  const int po = blockIdx.x * 4 + pq;
  const float sc = scale[c], sh = shift[c];
  const size_t row0 = ((size_t)(n * 56 + 2 * po)) * 56 * 64 + c;
  #pragma unroll
  for (int q4 = 0; q4 < 7; ++q4) {
    u16 pk[4];
    #pragma unroll
    for (int i = 0; i < 4; ++i) {
      const int qo = q4 * 4 + i;
      const size_t b = row0 + (size_t)(2 * qo) * 64;
      const float v0 = fmaf(bf2f(y3[b]), sc, sh);
      const float v1 = fmaf(bf2f(y3[b + 64]), sc, sh);
      const float v2 = fmaf(bf2f(y3[b + 56 * 64]), sc, sh);
      const float v3 = fmaf(bf2f(y3[b + 56 * 64 + 64]), sc, sh);
      pk[i] = f2bf(fmaxf(fmaxf(fmaxf(v0, v1), fmaxf(v2, v3)), 0.f));
    }
    uint2 w;
    w.x = (u32)pk[0] | ((u32)pk[1] << 16);
    w.y = (u32)pk[2] | ((u32)pk[3] << 16);
    *reinterpret_cast<uint2*>(x3t + (((size_t)(n * 64 + c) * 28 + po) * 28 + q4 * 4)) = w;
  }
}

// ------------- fc1: x3t bf16 [64,50176] @ w fp32 [256,50176]^T --------------
__global__ __launch_bounds__(256)
void k_fc1(const u16* __restrict__ x3t, const float* __restrict__ w,
           float* __restrict__ partial) {
  const int ks = blockIdx.x, nt = blockIdx.y;
  const int t = threadIdx.x;
  const int tm = t >> 4, tn = t & 15;
  __shared__ __align__(16) float xs[64][68];
  __shared__ __align__(16) float wsx[64][68];
  float acc[4][4];
  #pragma unroll
  for (int i = 0; i < 4; ++i)
    #pragma unroll
    for (int j = 0; j < 4; ++j) acc[i][j] = 0.f;
  for (int chn = 0; chn < 14; ++chn) {
    const int kb = ks * 896 + chn * 64;
    #pragma unroll
    for (int i = 0; i < 4; ++i) {
      const int idx = t + 256 * i;
      const int row = idx >> 4, c4 = (idx & 15) * 4;
      const ushort4 xv = *reinterpret_cast<const ushort4*>(x3t + (size_t)row * 50176 + kb + c4);
      xs[row][c4 + 0] = bf2f(xv.x); xs[row][c4 + 1] = bf2f(xv.y);
      xs[row][c4 + 2] = bf2f(xv.z); xs[row][c4 + 3] = bf2f(xv.w);
      *reinterpret_cast<float4*>(&wsx[row][c4]) =
          ldg4(w + (size_t)(nt * 64 + row) * 50176 + kb + c4);
    }
    __syncthreads();
    #pragma unroll
    for (int k4 = 0; k4 < 16; ++k4) {
      float4 xr[4], wr[4];
      #pragma unroll
      for (int i = 0; i < 4; ++i)
        xr[i] = *reinterpret_cast<const float4*>(&xs[tm + 16 * i][k4 * 4]);
      #pragma unroll
      for (int j = 0; j < 4; ++j)
        wr[j] = *reinterpret_cast<const float4*>(&wsx[tn * 4 + j][k4 * 4]);
      #pragma unroll
      for (int i = 0; i < 4; ++i)
        #pragma unroll
        for (int j = 0; j < 4; ++j) {
          float a = acc[i][j];
          a = fmaf(xr[i].x, wr[j].x, a);
          a = fmaf(xr[i].y, wr[j].y, a);
          a = fmaf(xr[i].z, wr[j].z, a);
          a = fmaf(xr[i].w, wr[j].w, a);
          acc[i][j] = a;
        }
    }
    __syncthreads();
  }
  #pragma unroll
  for (int j = 0; j < 4; ++j)
    #pragma unroll
    for (int i = 0; i < 4; ++i)
      partial[(size_t)ks * 16384 + (nt * 64 + tn * 4 + j) * 64 + tm + 16 * i] = acc[i][j];
}

__global__ __launch_bounds__(256)
void k_fc1_reduce(const float* __restrict__ partial, const float* __restrict__ b1f,
                  float* __restrict__ h1) {
  const int idx = blockIdx.x * 256 + threadIdx.x;  // 16384, idx = nn*64+m
  const int nn = idx >> 6, m = idx & 63;
  float s = b1f[nn];
  for (int k = 0; k < 56; ++k) s += partial[(size_t)k * 16384 + idx];
  h1[(size_t)m * 256 + nn] = fmaxf(s, 0.f);
}

__global__ __launch_bounds__(320)
void k_fc2(const float* __restrict__ h1, const float* __restrict__ w2f,
           const float* __restrict__ b2f, float* __restrict__ out) {
  const int t = threadIdx.x;
  const int m = t / 5, o = t - m * 5;
  float s = b2f[o];
  const float* hr = h1 + (size_t)m * 256;
  const float* wr = w2f + (size_t)o * 256;
  for (int j = 0; j < 256; j += 4) {
    const float4 h = ldg4(hr + j);
    const float4 w = ldg4(wr + j);
    s = fmaf(h.x, w.x, s); s = fmaf(h.y, w.y, s);
    s = fmaf(h.z, w.z, s); s = fmaf(h.w, w.w, s);
  }
  out[m * 5 + o] = s;
}

// ---------------------------------------------------------------------------
extern "C" void kernel_launch(void* const* d_in, const int* in_sizes, int n_in,
                              void* d_out, int out_size, void* d_ws, size_t ws_size,
                              hipStream_t stream) {
  (void)in_sizes; (void)n_in; (void)out_size; (void)ws_size;
  const float* d   = (const float*)d_in[0];
  const float* w1  = (const float*)d_in[1];
  const float* b1  = (const float*)d_in[2];
  const float* g1  = (const float*)d_in[3];
  const float* be1 = (const float*)d_in[4];
  const float* w2  = (const float*)d_in[5];
  const float* b2  = (const float*)d_in[6];
  const float* g2  = (const float*)d_in[7];
  const float* be2 = (const float*)d_in[8];
  const float* w3  = (const float*)d_in[9];
  const float* b3  = (const float*)d_in[10];
  const float* g3  = (const float*)d_in[11];
  const float* be3 = (const float*)d_in[12];
  const float* fw1 = (const float*)d_in[13];
  const float* fb1 = (const float*)d_in[14];
  const float* fw2 = (const float*)d_in[15];
  const float* fb2 = (const float*)d_in[16];
  float* out = (float*)d_out;
  float* ws  = (float*)d_ws;

  u16* x1   = (u16*)(ws + WS_X1);
  u16* y2   = (u16*)(ws + WS_Y2);
  u16* y3   = (u16*)(ws + WS_Y2);   // alias (y2 dead by then)
  u16* x2   = (u16*)(ws + WS_X2);
  u16* x3t  = (u16*)(ws + WS_X3T);
  u16* wt2  = (u16*)(ws + WS_WT2);
  u16* wt3  = (u16*)(ws + WS_WT3);
  float* p1 = ws + WS_P1;
  float* p2 = ws + WS_P2;
  float* p3 = ws + WS_P3;
  float* st = ws + WS_ST;
  float* fcp = ws + WS_FCP;
  float* h1 = ws + WS_H1;

  k_prep_w<<<96, 256, 0, stream>>>(w2, w3, wt2, wt3);
  // layer 1
  k_conv1_stats<<<dim3(26, 64), 256, 0, stream>>>(d, w1, b1, p1);
  k_finalize<<<16, 256, 0, stream>>>(p1, 1664, 3240000.0, g1, be1, st + 0, st + 16);
  k_conv1_pool<<<dim3(49, 64), 256, 0, stream>>>(d, w1, b1, st, x1);
  // layer 2
  k_conv2<<<dim3(7, 7, 64), 256, 0, stream>>>(x1, wt2, b2, y2, p2);
  k_finalize<<<32, 256, 0, stream>>>(p2, 12544, 802816.0, g2, be2, st + 32, st + 64);
  k_bnpool2<<<3136, 256, 0, stream>>>(y2, st + 32, st + 64, x2);
  // layer 3
  k_conv3<<<dim3(4, 7, 64), 256, 0, stream>>>(x2, wt3, b3, y3, p3);
  k_finalize<<<64, 256, 0, stream>>>(p3, 3584, 200704.0, g3, be3, st + 96, st + 160);
  k_bnpool3<<<dim3(7, 64), 256, 0, stream>>>(y3, st + 96, st + 160, x3t);
  // fc
  k_fc1<<<dim3(56, 4), 256, 0, stream>>>(x3t, fw1, fcp);
  k_fc1_reduce<<<64, 256, 0, stream>>>(fcp, fb1, h1);
  k_fc2<<<1, 320, 0, stream>>>(h1, fw2, fb2, out);
}

// Round 4
// 218.524 us; speedup vs baseline: 2.8232x; 1.3015x over previous
//
#include <hip/hip_runtime.h>
#include <cstdint>
#include <cstddef>

// ---------------------------------------------------------------------------
// Plant_Identifier CNN forward.
// conv1 fp32 (stats pass + fused pool pass, NHWC bf16 out)
// conv2/conv3: bf16 MFMA implicit-GEMM (16x16x32), fused per-wave BN stats
// bnpool: bf16 elementwise; bnpool3 fuses NHWC->NCHW transpose for fc1
// fc1: zero-LDS MFMA K-split GEMM, fp32 weights -> in-register bf16 hi/lo
// All reductions deterministic (two-stage partials).
// R4: fc1 rewritten (was 117us @ 9.7% occupancy, 224 blocks, LDS-conflicted).
// ---------------------------------------------------------------------------

typedef __attribute__((ext_vector_type(8))) short sh8_t;   // 8 x bf16
typedef __attribute__((ext_vector_type(4))) float f4_t;    // mfma acc
typedef unsigned short u16;
typedef unsigned int u32;

// workspace layout (float units)
#define WS_X1   ((size_t)0)          // x1  bf16 [64,112,112,16] -> 6,422,528 slots
#define WS_Y2   ((size_t)6422528)    // y2  bf16 [64,112,112,32] (12,845,056); later y3 [64,56,56,64]
#define WS_X2   ((size_t)19267584)   // x2  bf16 [64,56,56,32] (3,211,264)
#define WS_X3T  ((size_t)22478848)   // x3t bf16 [64,64*28*28] (1,605,632)
#define WS_WT2  ((size_t)24084480)   // wt2 bf16 [32][3][4][16] (3,072 slots)
#define WS_WT3  ((size_t)24087552)   // wt3 bf16 [64][3][3][32] (9,216 slots)
#define WS_P1   ((size_t)24096768)   // 16*2*1664  = 53,248
#define WS_P2   ((size_t)24150016)   // 32*2*12544 = 802,816
#define WS_P3   ((size_t)24952832)   // 64*2*3584  = 458,752
#define WS_ST   ((size_t)25411584)   // 224: scale/shift 16,16,32,32,64,64
#define WS_FCP  ((size_t)25411808)   // 224*16384 = 3,670,016
#define WS_H1   ((size_t)29081824)   // 16,384
// total 29,098,208 floats = 116.4 MB

static __device__ __forceinline__ float4 ldg4(const float* p) {
  return *reinterpret_cast<const float4*>(p);
}
static __device__ __forceinline__ float bf2f(u16 u) {
  union { u32 i; float f; } c; c.i = ((u32)u) << 16; return c.f;
}
static __device__ __forceinline__ u16 f2bf(float f) {
  union { float f; u32 i; } c; c.f = f;
  const u32 x = c.i;
  return (u16)((x + 0x7fffu + ((x >> 16) & 1u)) >> 16);   // RNE
}

// ---------------- weight prep: fp32 OIHW -> bf16 co-major K layouts ---------
__global__ __launch_bounds__(256)
void k_prep_w(const float* __restrict__ w2, const float* __restrict__ w3,
              u16* __restrict__ wt2, u16* __restrict__ wt3) {
  const int t = blockIdx.x * 256 + threadIdx.x;  // 24576 total
  if (t < 6144) {  // wt2 [co32][kh3][kwp4][ci16], kw=3 zero-padded
    const int ci = t & 15, kwp = (t >> 4) & 3, kh = (t >> 6) % 3, co = t / 192;
    float v = 0.f;
    if (kwp < 3) v = w2[((co * 16 + ci) * 3 + kh) * 3 + kwp];
    wt2[t] = f2bf(v);
  } else {         // wt3 [co64][kh3][kw3][ci32]
    const int u = t - 6144;
    const int ci = u & 31, kw = (u >> 5) % 3, kh = (u / 96) % 3, co = u / 288;
    wt3[u] = f2bf(w3[((co * 32 + ci) * 3 + kh) * 3 + kw]);
  }
}

// ---------------- conv1 stats pass (recompute, all 16 co per thread) --------
// grid (26, 64), 256 thr; thread = 8-px run of the 225x225 pre-pool map.
__global__ __launch_bounds__(256)
void k_conv1_stats(const float* __restrict__ d, const float* __restrict__ w1,
                   const float* __restrict__ b1, float* __restrict__ part) {
  const int n = blockIdx.y;
  const int t = threadIdx.x;
  const int slot = blockIdx.x * 256 + t;  // over 225*29 = 6525
  const int oh = slot / 29, q = slot - oh * 29;
  float sum[16], sq[16];
  #pragma unroll
  for (int co = 0; co < 16; ++co) { sum[co] = 0.f; sq[co] = 0.f; }
  if (slot < 6525) {
    float pa[2][3][12];  // rows {oh-1, oh}, 3 ci, cols 8q-4..8q+7
    #pragma unroll
    for (int r = 0; r < 2; ++r) {
      const int ih = oh - 1 + r;
      const bool rv = (unsigned)ih < 224u;
      #pragma unroll
      for (int ci = 0; ci < 3; ++ci) {
        const float* rp = d + ((size_t)(n * 3 + ci) * 224 + ih) * 224;
        #pragma unroll
        for (int ch = 0; ch < 3; ++ch) {
          const int c0 = 8 * q - 4 + 4 * ch;
          float4 v = make_float4(0.f, 0.f, 0.f, 0.f);
          if (rv && c0 >= 0 && c0 <= 220) v = ldg4(rp + c0);
          pa[r][ci][ch * 4 + 0] = v.x; pa[r][ci][ch * 4 + 1] = v.y;
          pa[r][ci][ch * 4 + 2] = v.z; pa[r][ci][ch * 4 + 3] = v.w;
        }
      }
    }
    #pragma unroll
    for (int co = 0; co < 16; ++co) {
      float wz[12];
      #pragma unroll
      for (int z = 0; z < 12; ++z) wz[z] = w1[co * 12 + z];
      const float bias = b1[co];
      #pragma unroll
      for (int p = 0; p < 8; ++p) {
        if (8 * q + p <= 224) {
          float v = bias;
          #pragma unroll
          for (int ci = 0; ci < 3; ++ci)
            #pragma unroll
            for (int kh = 0; kh < 2; ++kh)
              #pragma unroll
              for (int kw = 0; kw < 2; ++kw)
                v = fmaf(pa[kh][ci][p + kw + 3], wz[ci * 4 + kh * 2 + kw], v);
          sum[co] += v;
          sq[co] = fmaf(v, v, sq[co]);
        }
      }
    }
  }
  // block tree-reduce: red[32][257]
  __shared__ float red[32][257];
  #pragma unroll
  for (int co = 0; co < 16; ++co) { red[co][t] = sum[co]; red[16 + co][t] = sq[co]; }
  __syncthreads();
  for (int off = 128; off > 0; off >>= 1) {
    if (t < off) {
      #pragma unroll
      for (int z = 0; z < 32; ++z) red[z][t] += red[z][t + off];
    }
    __syncthreads();
  }
  if (t < 16) {
    const int p = n * 26 + blockIdx.x;  // P1 = 1664
    part[(t * 2 + 0) * 1664 + p] = red[t][0];
    part[(t * 2 + 1) * 1664 + p] = red[16 + t][0];
  }
}

// ------------- finalize: partials -> per-channel scale/shift ----------------
__global__ __launch_bounds__(256)
void k_finalize(const float* __restrict__ part, int P, double count,
                const float* __restrict__ g, const float* __restrict__ bta,
                float* __restrict__ scale, float* __restrict__ shift) {
  const int c = blockIdx.x;
  double s = 0.0, sq = 0.0;
  for (int i = threadIdx.x; i < P; i += 256) {
    s  += (double)part[(size_t)(c * 2 + 0) * P + i];
    sq += (double)part[(size_t)(c * 2 + 1) * P + i];
  }
  __shared__ double rs[256], rq[256];
  rs[threadIdx.x] = s; rq[threadIdx.x] = sq;
  __syncthreads();
  for (int off = 128; off > 0; off >>= 1) {
    if (threadIdx.x < off) {
      rs[threadIdx.x] += rs[threadIdx.x + off];
      rq[threadIdx.x] += rq[threadIdx.x + off];
    }
    __syncthreads();
  }
  if (threadIdx.x == 0) {
    const double mean = rs[0] / count;
    const double var  = rq[0] / count - mean * mean;
    const double rstd = 1.0 / sqrt(var + 1e-5);
    const double sc = (double)g[c] * rstd;
    scale[c] = (float)sc;
    shift[c] = (float)((double)bta[c] - mean * sc);
  }
}

// ------------- conv1 + BN + ReLU + pool fused -> x1 NHWC bf16 ---------------
__global__ __launch_bounds__(256)
void k_conv1_pool(const float* __restrict__ d, const float* __restrict__ w1,
                  const float* __restrict__ b1, const float* __restrict__ st,
                  u16* __restrict__ x1) {
  const int n = blockIdx.y;
  const int s = blockIdx.x * 256 + threadIdx.x;  // 12544
  const int po = s / 112, qo = s - po * 112;
  float pa[3][3][4];
  #pragma unroll
  for (int r = 0; r < 3; ++r) {
    const int ih = 2 * po - 1 + r;
    const bool rv = (unsigned)ih < 224u;
    #pragma unroll
    for (int ci = 0; ci < 3; ++ci) {
      const float* rp = d + ((size_t)(n * 3 + ci) * 224 + ih) * 224;
      float2 a = make_float2(0.f, 0.f), b = make_float2(0.f, 0.f);
      if (rv) {
        if (qo > 0) a = *reinterpret_cast<const float2*>(rp + 2 * qo - 2);
        b = *reinterpret_cast<const float2*>(rp + 2 * qo);
      }
      pa[r][ci][0] = a.x; pa[r][ci][1] = a.y;
      pa[r][ci][2] = b.x; pa[r][ci][3] = b.y;
    }
  }
  u16 outv[16];
  #pragma unroll
  for (int co = 0; co < 16; ++co) {
    const float bias = b1[co];
    float acc[2][2] = {{bias, bias}, {bias, bias}};
    #pragma unroll
    for (int ci = 0; ci < 3; ++ci)
      #pragma unroll
      for (int kh = 0; kh < 2; ++kh)
        #pragma unroll
        for (int kw = 0; kw < 2; ++kw) {
          const float w = w1[co * 12 + ci * 4 + kh * 2 + kw];
          #pragma unroll
          for (int dy = 0; dy < 2; ++dy)
            #pragma unroll
            for (int dx = 0; dx < 2; ++dx)
              acc[dy][dx] = fmaf(pa[dy + kh][ci][dx + kw + 1], w, acc[dy][dx]);
        }
    const float sc = st[co], sh = st[16 + co];
    const float v00 = fmaxf(fmaf(acc[0][0], sc, sh), 0.f);
    const float v01 = fmaxf(fmaf(acc[0][1], sc, sh), 0.f);
    const float v10 = fmaxf(fmaf(acc[1][0], sc, sh), 0.f);
    const float v11 = fmaxf(fmaf(acc[1][1], sc, sh), 0.f);
    outv[co] = f2bf(fmaxf(fmaxf(v00, v01), fmaxf(v10, v11)));
  }
  u16* o = x1 + ((size_t)((n * 112 + po) * 112 + qo)) * 16;
  u32 pk[8];
  #pragma unroll
  for (int k = 0; k < 8; ++k) pk[k] = (u32)outv[2 * k] | ((u32)outv[2 * k + 1] << 16);
  *reinterpret_cast<int4*>(o)     = make_int4(pk[0], pk[1], pk[2], pk[3]);
  *reinterpret_cast<int4*>(o + 8) = make_int4(pk[4], pk[5], pk[6], pk[7]);
}

// ------------- conv2: bf16 MFMA, CI=16 CO=32 H=112, kw padded to 4 ----------
// grid (7 owt, 7 strip, 64 n), 256 thr. wave = 4 oh rows x 16 ow x 32 co.
__global__ __launch_bounds__(256)
void k_conv2(const u16* __restrict__ x1, const u16* __restrict__ wt2,
             const float* __restrict__ b2, u16* __restrict__ y2,
             float* __restrict__ part) {
  const int ow0 = blockIdx.x * 16, oh0 = blockIdx.y * 16, n = blockIdx.z;
  const int t = threadIdx.x, lane = t & 63, wv = t >> 6;
  const int g = lane >> 4, li = lane & 15;
  __shared__ __align__(16) unsigned char tile[18 * 640];  // rows x 20px x 32B
  // stage x1 tile: rows oh0-1..oh0+16, cols ow0-1..ow0+18 (zero halo)
  for (int idx = t; idx < 720; idx += 256) {
    const int rr = idx / 40, rem = idx - rr * 40, p = rem >> 1, c = rem & 1;
    const int ih = oh0 - 1 + rr, iw = ow0 - 1 + p;
    int4 v = make_int4(0, 0, 0, 0);
    if ((unsigned)ih < 112u && (unsigned)iw < 112u)
      v = *reinterpret_cast<const int4*>(x1 + ((size_t)((n * 112 + ih) * 112 + iw) * 16 + c * 8));
    *reinterpret_cast<int4*>(tile + ((rr * 640 + p * 32 + c * 16) ^ (((p >> 2) & 1) << 4))) = v;
  }
  // weights: W[cot][kh][m], k64 = kw*16+ci, kw=2m+(g>>1), ci=8(g&1)+j
  sh8_t W[2][3][2];
  #pragma unroll
  for (int cot = 0; cot < 2; ++cot)
    #pragma unroll
    for (int kh = 0; kh < 3; ++kh)
      #pragma unroll
      for (int m = 0; m < 2; ++m)
        W[cot][kh][m] = *reinterpret_cast<const sh8_t*>(
            wt2 + ((cot * 16 + li) * 192 + kh * 64 + m * 32 + g * 8));
  f4_t acc[4][2];
  #pragma unroll
  for (int r = 0; r < 4; ++r) { acc[r][0] = (f4_t)0.f; acc[r][1] = (f4_t)0.f; }
  __syncthreads();
  const int rowb = 4 * wv;
  #pragma unroll
  for (int ihr = 0; ihr < 6; ++ihr) {
    const int row = rowb + ihr;
    #pragma unroll
    for (int m = 0; m < 2; ++m) {
      const int p = li + 2 * m + (g >> 1);
      const sh8_t B = *reinterpret_cast<const sh8_t*>(
          tile + ((row * 640 + p * 32 + (g & 1) * 16) ^ (((p >> 2) & 1) << 4)));
      #pragma unroll
      for (int kh = 0; kh < 3; ++kh) {
        const int r = ihr - kh;
        if (r >= 0 && r < 4) {
          acc[r][0] = __builtin_amdgcn_mfma_f32_16x16x32_bf16(W[0][kh][m], B, acc[r][0], 0, 0, 0);
          acc[r][1] = __builtin_amdgcn_mfma_f32_16x16x32_bf16(W[1][kh][m], B, acc[r][1], 0, 0, 0);
        }
      }
    }
  }
  // epilogue: bias, store bf16, fused stats. lane co = cot*16 + 4g + j
  f4_t bias[2], ssum[2], ssq[2];
  bias[0] = *reinterpret_cast<const f4_t*>(b2 + 4 * g);
  bias[1] = *reinterpret_cast<const f4_t*>(b2 + 16 + 4 * g);
  ssum[0] = (f4_t)0.f; ssum[1] = (f4_t)0.f; ssq[0] = (f4_t)0.f; ssq[1] = (f4_t)0.f;
  const int ohb = oh0 + 4 * wv;
  #pragma unroll
  for (int r = 0; r < 4; ++r)
    #pragma unroll
    for (int cot = 0; cot < 2; ++cot) {
      const f4_t y = acc[r][cot] + bias[cot];
      ssum[cot] += y; ssq[cot] += y * y;
      const size_t off = ((size_t)((n * 112 + ohb + r) * 112 + ow0 + li)) * 32 + cot * 16 + 4 * g;
      uint2 pk;
      pk.x = (u32)f2bf(y[0]) | ((u32)f2bf(y[1]) << 16);
      pk.y = (u32)f2bf(y[2]) | ((u32)f2bf(y[3]) << 16);
      *reinterpret_cast<uint2*>(y2 + off) = pk;
    }
  #pragma unroll
  for (int msk = 1; msk < 16; msk <<= 1)
    #pragma unroll
    for (int cot = 0; cot < 2; ++cot)
      #pragma unroll
      for (int j = 0; j < 4; ++j) {
        ssum[cot][j] += __shfl_xor(ssum[cot][j], msk);
        ssq[cot][j]  += __shfl_xor(ssq[cot][j], msk);
      }
  if (li == 0) {
    const int slot = (((n * 7 + (int)blockIdx.y) * 7 + (int)blockIdx.x)) * 4 + wv;  // 12544
    #pragma unroll
    for (int cot = 0; cot < 2; ++cot)
      #pragma unroll
      for (int j = 0; j < 4; ++j) {
        const int co = cot * 16 + 4 * g + j;
        part[(size_t)(co * 2 + 0) * 12544 + slot] = ssum[cot][j];
        part[(size_t)(co * 2 + 1) * 12544 + slot] = ssq[cot][j];
      }
  }
}

// ------------- conv3: bf16 MFMA, CI=32 CO=64 H=56 ---------------------------
// grid (4 owt, 7 strip, 64 n), 256 thr. wave = (rowhalf, cohalf): 4 rows x 32 co.
__global__ __launch_bounds__(256)
void k_conv3(const u16* __restrict__ x2, const u16* __restrict__ wt3,
             const float* __restrict__ b3, u16* __restrict__ y3,
             float* __restrict__ part) {
  const int ow0 = blockIdx.x * 16, oh0 = blockIdx.y * 8, n = blockIdx.z;
  const int t = threadIdx.x, lane = t & 63, wv = t >> 6;
  const int rh = wv & 1, ch = wv >> 1;
  const int g = lane >> 4, li = lane & 15;
  __shared__ __align__(16) unsigned char tile[10 * 1152];  // rows x 18px x 64B
  for (int idx = t; idx < 720; idx += 256) {
    const int rr = idx / 72, rem = idx - rr * 72, p = rem >> 2, c = rem & 3;
    const int ih = oh0 - 1 + rr, iw = ow0 - 1 + p;
    int4 v = make_int4(0, 0, 0, 0);
    if ((unsigned)ih < 56u && (unsigned)iw < 56u)
      v = *reinterpret_cast<const int4*>(x2 + ((size_t)((n * 56 + ih) * 56 + iw) * 32 + c * 8));
    *reinterpret_cast<int4*>(tile + ((rr * 1152 + p * 64 + c * 16) ^ (((p >> 1) & 3) << 4))) = v;
  }
  sh8_t W[2][3][3];
  #pragma unroll
  for (int c2 = 0; c2 < 2; ++c2)
    #pragma unroll
    for (int kh = 0; kh < 3; ++kh)
      #pragma unroll
      for (int kw = 0; kw < 3; ++kw)
        W[c2][kh][kw] = *reinterpret_cast<const sh8_t*>(
            wt3 + ((size_t)(ch * 32 + c2 * 16 + li) * 288 + (kh * 3 + kw) * 32 + g * 8));
  f4_t acc[4][2];
  #pragma unroll
  for (int r = 0; r < 4; ++r) { acc[r][0] = (f4_t)0.f; acc[r][1] = (f4_t)0.f; }
  __syncthreads();
  const int rowb = 4 * rh;
  #pragma unroll
  for (int ihr = 0; ihr < 6; ++ihr) {
    const int row = rowb + ihr;
    #pragma unroll
    for (int kw = 0; kw < 3; ++kw) {
      const int p = li + kw;
      const sh8_t B = *reinterpret_cast<const sh8_t*>(
          tile + ((row * 1152 + p * 64 + g * 16) ^ (((p >> 1) & 3) << 4)));
      #pragma unroll
      for (int kh = 0; kh < 3; ++kh) {
        const int r = ihr - kh;
        if (r >= 0 && r < 4) {
          acc[r][0] = __builtin_amdgcn_mfma_f32_16x16x32_bf16(W[0][kh][kw], B, acc[r][0], 0, 0, 0);
          acc[r][1] = __builtin_amdgcn_mfma_f32_16x16x32_bf16(W[1][kh][kw], B, acc[r][1], 0, 0, 0);
        }
      }
    }
  }
  const int ow = ow0 + li;
  const bool valid = ow < 56;
  f4_t bias[2], ssum[2], ssq[2];
  bias[0] = *reinterpret_cast<const f4_t*>(b3 + ch * 32 + 4 * g);
  bias[1] = *reinterpret_cast<const f4_t*>(b3 + ch * 32 + 16 + 4 * g);
  ssum[0] = (f4_t)0.f; ssum[1] = (f4_t)0.f; ssq[0] = (f4_t)0.f; ssq[1] = (f4_t)0.f;
  const int ohb = oh0 + 4 * rh;
  #pragma unroll
  for (int r = 0; r < 4; ++r)
    #pragma unroll
    for (int c2 = 0; c2 < 2; ++c2) {
      const f4_t y = acc[r][c2] + bias[c2];
      if (valid) {
        ssum[c2] += y; ssq[c2] += y * y;
        const size_t off = ((size_t)((n * 56 + ohb + r) * 56 + ow)) * 64 + ch * 32 + c2 * 16 + 4 * g;
        uint2 pk;
        pk.x = (u32)f2bf(y[0]) | ((u32)f2bf(y[1]) << 16);
        pk.y = (u32)f2bf(y[2]) | ((u32)f2bf(y[3]) << 16);
        *reinterpret_cast<uint2*>(y3 + off) = pk;
      }
    }
  #pragma unroll
  for (int msk = 1; msk < 16; msk <<= 1)
    #pragma unroll
    for (int c2 = 0; c2 < 2; ++c2)
      #pragma unroll
      for (int j = 0; j < 4; ++j) {
        ssum[c2][j] += __shfl_xor(ssum[c2][j], msk);
        ssq[c2][j]  += __shfl_xor(ssq[c2][j], msk);
      }
  if (li == 0) {
    const int slot = (((n * 7 + (int)blockIdx.y) * 4 + (int)blockIdx.x)) * 2 + rh;  // 3584
    #pragma unroll
    for (int c2 = 0; c2 < 2; ++c2)
      #pragma unroll
      for (int j = 0; j < 4; ++j) {
        const int co = ch * 32 + c2 * 16 + 4 * g + j;
        part[(size_t)(co * 2 + 0) * 3584 + slot] = ssum[c2][j];
        part[(size_t)(co * 2 + 1) * 3584 + slot] = ssq[c2][j];
      }
  }
}

// ------------- bnpool2: y2 bf16 NHWC -> x2 bf16 NHWC ------------------------
__global__ __launch_bounds__(256)
void k_bnpool2(const u16* __restrict__ y2, const float* __restrict__ scale,
               const float* __restrict__ shift, u16* __restrict__ x2) {
  const int idx = blockIdx.x * 256 + threadIdx.x;  // 802816
  const int cg = idx & 3;
  int rest = idx >> 2;
  const int qo = rest % 56; rest /= 56;
  const int po = rest % 56;
  const int n = rest / 56;
  const size_t base = ((size_t)((n * 112 + 2 * po) * 112 + 2 * qo)) * 32 + cg * 8;
  const int4 r00 = *reinterpret_cast<const int4*>(y2 + base);
  const int4 r01 = *reinterpret_cast<const int4*>(y2 + base + 32);
  const int4 r10 = *reinterpret_cast<const int4*>(y2 + base + 112 * 32);
  const int4 r11 = *reinterpret_cast<const int4*>(y2 + base + 112 * 32 + 32);
  const u32* a = reinterpret_cast<const u32*>(&r00);
  const u32* b = reinterpret_cast<const u32*>(&r01);
  const u32* c = reinterpret_cast<const u32*>(&r10);
  const u32* e = reinterpret_cast<const u32*>(&r11);
  u16 outv[8];
  #pragma unroll
  for (int j = 0; j < 8; ++j) {
    const int dw = j >> 1, hs = (j & 1) * 16;
    const float sc = scale[cg * 8 + j], sh = shift[cg * 8 + j];
    const float v0 = fmaf(bf2f((u16)(a[dw] >> hs)), sc, sh);
    const float v1 = fmaf(bf2f((u16)(b[dw] >> hs)), sc, sh);
    const float v2 = fmaf(bf2f((u16)(c[dw] >> hs)), sc, sh);
    const float v3 = fmaf(bf2f((u16)(e[dw] >> hs)), sc, sh);
    outv[j] = f2bf(fmaxf(fmaxf(fmaxf(v0, v1), fmaxf(v2, v3)), 0.f));
  }
  u32 pk[4];
  #pragma unroll
  for (int k = 0; k < 4; ++k) pk[k] = (u32)outv[2 * k] | ((u32)outv[2 * k + 1] << 16);
  *reinterpret_cast<int4*>(x2 + ((size_t)((n * 56 + po) * 56 + qo)) * 32 + cg * 8) =
      make_int4(pk[0], pk[1], pk[2], pk[3]);
}

// ------------- bnpool3: y3 bf16 NHWC -> x3t bf16 NCHW (fc1 order) -----------
// grid (7, 64), 256 thr: thread = (c 0..63, po-quarter 0..3), full qo row.
__global__ __launch_bounds__(256)
void k_bnpool3(const u16* __restrict__ y3, const float* __restrict__ scale,
               const float* __restrict__ shift, u16* __restrict__ x3t) {
  const int n = blockIdx.y;
  const int c = threadIdx.x & 63, pq = threadIdx.x >> 6;
  const int po = blockIdx.x * 4 + pq;
  const float sc = scale[c], sh = shift[c];
  const size_t row0 = ((size_t)(n * 56 + 2 * po)) * 56 * 64 + c;
  #pragma unroll
  for (int q4 = 0; q4 < 7; ++q4) {
    u16 pk[4];
    #pragma unroll
    for (int i = 0; i < 4; ++i) {
      const int qo = q4 * 4 + i;
      const size_t b = row0 + (size_t)(2 * qo) * 64;
      const float v0 = fmaf(bf2f(y3[b]), sc, sh);
      const float v1 = fmaf(bf2f(y3[b + 64]), sc, sh);
      const float v2 = fmaf(bf2f(y3[b + 56 * 64]), sc, sh);
      const float v3 = fmaf(bf2f(y3[b + 56 * 64 + 64]), sc, sh);
      pk[i] = f2bf(fmaxf(fmaxf(fmaxf(v0, v1), fmaxf(v2, v3)), 0.f));
    }
    uint2 w;
    w.x = (u32)pk[0] | ((u32)pk[1] << 16);
    w.y = (u32)pk[2] | ((u32)pk[3] << 16);
    *reinterpret_cast<uint2*>(x3t + (((size_t)(n * 64 + c) * 28 + po) * 28 + q4 * 4)) = w;
  }
}

// ------------- fc1: zero-LDS MFMA K-split GEMM ------------------------------
// x3t bf16 [64 m][50176 k]  @  w fp32 [256 n][50176 k]^T -> partial[224][256][64]
// grid (224 kc, 4 nt), 256 thr. wave wv: n-rows n0=nt*64+wv*16, all 64 m.
// w loaded fp32 -> in-register bf16 hi/lo split (2 MFMA per k32).
// A-frag lane(g,li): row n0+li, k = g*8+j.  B-frag: col m=mf*16+li, k = g*8+j.
__global__ __launch_bounds__(256)
void k_fc1(const u16* __restrict__ x3t, const float* __restrict__ w,
           float* __restrict__ partial) {
  const int kc = blockIdx.x, nt = blockIdx.y;
  const int t = threadIdx.x, lane = t & 63, wv = t >> 6;
  const int g = lane >> 4, li = lane & 15;
  const int n0 = nt * 64 + wv * 16;
  const float* wrow = w + (size_t)(n0 + li) * 50176 + kc * 224;
  const u16* xbase = x3t + kc * 224;
  f4_t acc[4];
  #pragma unroll
  for (int mf = 0; mf < 4; ++mf) acc[mf] = (f4_t)0.f;
  #pragma unroll
  for (int ks = 0; ks < 7; ++ks) {  // 7 x k32
    const int kb = ks * 32 + g * 8;
    const float4 wa = ldg4(wrow + kb);
    const float4 wb = ldg4(wrow + kb + 4);
    float wf[8] = {wa.x, wa.y, wa.z, wa.w, wb.x, wb.y, wb.z, wb.w};
    sh8_t hi, lo;
    #pragma unroll
    for (int j = 0; j < 8; ++j) {
      const u16 h = f2bf(wf[j]);
      hi[j] = (short)h;
      lo[j] = (short)f2bf(wf[j] - bf2f(h));
    }
    #pragma unroll
    for (int mf = 0; mf < 4; ++mf) {
      const sh8_t B = *reinterpret_cast<const sh8_t*>(
          xbase + (size_t)(mf * 16 + li) * 50176 + kb);
      acc[mf] = __builtin_amdgcn_mfma_f32_16x16x32_bf16(hi, B, acc[mf], 0, 0, 0);
      acc[mf] = __builtin_amdgcn_mfma_f32_16x16x32_bf16(lo, B, acc[mf], 0, 0, 0);
    }
  }
  // C/D: col = li (m-within-frag), row = 4g + j (n-within-16)
  float* pb = partial + (size_t)kc * 16384;
  #pragma unroll
  for (int mf = 0; mf < 4; ++mf)
    #pragma unroll
    for (int j = 0; j < 4; ++j)
      pb[(size_t)(n0 + 4 * g + j) * 64 + mf * 16 + li] = acc[mf][j];
}

__global__ __launch_bounds__(256)
void k_fc1_reduce(const float* __restrict__ partial, const float* __restrict__ b1f,
                  float* __restrict__ h1) {
  const int idx = blockIdx.x * 256 + threadIdx.x;  // 16384, idx = nn*64+m
  const int nn = idx >> 6, m = idx & 63;
  float s = b1f[nn];
  for (int k = 0; k < 224; ++k) s += partial[(size_t)k * 16384 + idx];
  h1[(size_t)m * 256 + nn] = fmaxf(s, 0.f);
}

__global__ __launch_bounds__(320)
void k_fc2(const float* __restrict__ h1, const float* __restrict__ w2f,
           const float* __restrict__ b2f, float* __restrict__ out) {
  const int t = threadIdx.x;
  const int m = t / 5, o = t - m * 5;
  float s = b2f[o];
  const float* hr = h1 + (size_t)m * 256;
  const float* wr = w2f + (size_t)o * 256;
  for (int j = 0; j < 256; j += 4) {
    const float4 h = ldg4(hr + j);
    const float4 w = ldg4(wr + j);
    s = fmaf(h.x, w.x, s); s = fmaf(h.y, w.y, s);
    s = fmaf(h.z, w.z, s); s = fmaf(h.w, w.w, s);
  }
  out[m * 5 + o] = s;
}

// ---------------------------------------------------------------------------
extern "C" void kernel_launch(void* const* d_in, const int* in_sizes, int n_in,
                              void* d_out, int out_size, void* d_ws, size_t ws_size,
                              hipStream_t stream) {
  (void)in_sizes; (void)n_in; (void)out_size; (void)ws_size;
  const float* d   = (const float*)d_in[0];
  const float* w1  = (const float*)d_in[1];
  const float* b1  = (const float*)d_in[2];
  const float* g1  = (const float*)d_in[3];
  const float* be1 = (const float*)d_in[4];
  const float* w2  = (const float*)d_in[5];
  const float* b2  = (const float*)d_in[6];
  const float* g2  = (const float*)d_in[7];
  const float* be2 = (const float*)d_in[8];
  const float* w3  = (const float*)d_in[9];
  const float* b3  = (const float*)d_in[10];
  const float* g3  = (const float*)d_in[11];
  const float* be3 = (const float*)d_in[12];
  const float* fw1 = (const float*)d_in[13];
  const float* fb1 = (const float*)d_in[14];
  const float* fw2 = (const float*)d_in[15];
  const float* fb2 = (const float*)d_in[16];
  float* out = (float*)d_out;
  float* ws  = (float*)d_ws;

  u16* x1   = (u16*)(ws + WS_X1);
  u16* y2   = (u16*)(ws + WS_Y2);
  u16* y3   = (u16*)(ws + WS_Y2);   // alias (y2 dead by then)
  u16* x2   = (u16*)(ws + WS_X2);
  u16* x3t  = (u16*)(ws + WS_X3T);
  u16* wt2  = (u16*)(ws + WS_WT2);
  u16* wt3  = (u16*)(ws + WS_WT3);
  float* p1 = ws + WS_P1;
  float* p2 = ws + WS_P2;
  float* p3 = ws + WS_P3;
  float* st = ws + WS_ST;
  float* fcp = ws + WS_FCP;
  float* h1 = ws + WS_H1;

  k_prep_w<<<96, 256, 0, stream>>>(w2, w3, wt2, wt3);
  // layer 1
  k_conv1_stats<<<dim3(26, 64), 256, 0, stream>>>(d, w1, b1, p1);
  k_finalize<<<16, 256, 0, stream>>>(p1, 1664, 3240000.0, g1, be1, st + 0, st + 16);
  k_conv1_pool<<<dim3(49, 64), 256, 0, stream>>>(d, w1, b1, st, x1);
  // layer 2
  k_conv2<<<dim3(7, 7, 64), 256, 0, stream>>>(x1, wt2, b2, y2, p2);
  k_finalize<<<32, 256, 0, stream>>>(p2, 12544, 802816.0, g2, be2, st + 32, st + 64);
  k_bnpool2<<<3136, 256, 0, stream>>>(y2, st + 32, st + 64, x2);
  // layer 3
  k_conv3<<<dim3(4, 7, 64), 256, 0, stream>>>(x2, wt3, b3, y3, p3);
  k_finalize<<<64, 256, 0, stream>>>(p3, 3584, 200704.0, g3, be3, st + 96, st + 160);
  k_bnpool3<<<dim3(7, 64), 256, 0, stream>>>(y3, st + 96, st + 160, x3t);
  // fc
  k_fc1<<<dim3(224, 4), 256, 0, stream>>>(x3t, fw1, fcp);
  k_fc1_reduce<<<64, 256, 0, stream>>>(fcp, fb1, h1);
  k_fc2<<<1, 320, 0, stream>>>(h1, fw2, fb2, out);
}